// Round 3
// baseline (1555.095 us; speedup 1.0000x reference)
//
#include <hip/hip_runtime.h>

#define HC 256    // H*C
#define CCH 64    // channels
#define NEG 0.2f

// ---------------- preprocessing ----------------

__global__ void deg_kernel(const int* __restrict__ dst,
                           const float* __restrict__ eattr,
                           int* __restrict__ cnt, float* __restrict__ sumf, int E) {
  int e = blockIdx.x * blockDim.x + threadIdx.x;
  if (e >= E) return;
  int d = dst[e];
  atomicAdd(&cnt[d], 1);
  atomicAdd(&sumf[d], eattr[e]);
}

// single-block scan over N counts -> exclusive rowptr; also loop_attr = sum/max(cnt,1)
__global__ void scan_kernel(const int* __restrict__ cnt, const float* __restrict__ sumf,
                            int* __restrict__ rowptr, float* __restrict__ loopat, int n) {
  __shared__ int wsum[16];
  __shared__ int carry_s;
  int tid = threadIdx.x, lane = tid & 63, w = tid >> 6;
  if (tid == 0) carry_s = 0;
  __syncthreads();
  for (int base = 0; base < n; base += 1024) {
    int i = base + tid;
    int v = (i < n) ? cnt[i] : 0;
    int s = v;
    #pragma unroll
    for (int off = 1; off < 64; off <<= 1) {
      int t = __shfl_up(s, off, 64);
      if (lane >= off) s += t;
    }
    if (lane == 63) wsum[w] = s;
    __syncthreads();
    int woff = 0;
    for (int j = 0; j < w; j++) woff += wsum[j];
    int excl = carry_s + woff + s - v;
    if (i < n) {
      rowptr[i] = excl;
      loopat[i] = sumf[i] / fmaxf((float)v, 1.0f);
    }
    __syncthreads();
    if (tid == 1023) carry_s = excl + v;
    __syncthreads();
  }
  if (threadIdx.x == 0) rowptr[n] = carry_s;
}

__global__ void csr_fill_kernel(const int* __restrict__ src,
                                const int* __restrict__ dst,
                                const float* __restrict__ eattr,
                                const int* __restrict__ rowptr,
                                int* __restrict__ fill,
                                int* __restrict__ csr_src, float* __restrict__ csr_ea, int E) {
  int e = blockIdx.x * blockDim.x + threadIdx.x;
  if (e >= E) return;
  int d = dst[e];
  int p = atomicAdd(&fill[d], 1);
  int slot = rowptr[d] + p;
  csr_src[slot] = src[e];
  csr_ea[slot] = eattr[e];
}

// ---------------- fp32 GEMM: out[n][0:256] = A[n][0:K] @ W[K][256] + bias ----------------

__global__ __launch_bounds__(256)
void gemm_bias(const float* __restrict__ A, const float* __restrict__ W,
               const float* __restrict__ bias, float* __restrict__ out,
               int nrows, int K) {
  __shared__ float As[16][68];   // [k][m], padded row stride
  __shared__ float Ws[16][64];   // [k][n]
  int bm = blockIdx.x * 64, bn = blockIdx.y * 64;
  int tx = threadIdx.x & 15, ty = threadIdx.x >> 4;
  int lrow = threadIdx.x >> 2;           // 0..63
  int lkk  = (threadIdx.x & 3) << 2;     // 0,4,8,12
  int wk   = threadIdx.x >> 6;           // 0..3
  int wcol = threadIdx.x & 63;
  float acc[4][4] = {};
  for (int k0 = 0; k0 < K; k0 += 16) {
    int arow = bm + lrow;
    float4 a = make_float4(0.f, 0.f, 0.f, 0.f);
    if (arow < nrows) a = *(const float4*)(A + (size_t)arow * K + k0 + lkk);
    As[lkk + 0][lrow] = a.x;
    As[lkk + 1][lrow] = a.y;
    As[lkk + 2][lrow] = a.z;
    As[lkk + 3][lrow] = a.w;
    #pragma unroll
    for (int i = 0; i < 4; i++)
      Ws[wk + 4 * i][wcol] = W[(size_t)(k0 + wk + 4 * i) * HC + bn + wcol];
    __syncthreads();
    #pragma unroll
    for (int k = 0; k < 16; k++) {
      float av[4], wvv[4];
      #pragma unroll
      for (int i = 0; i < 4; i++) av[i] = As[k][ty * 4 + i];
      #pragma unroll
      for (int j = 0; j < 4; j++) wvv[j] = Ws[k][tx * 4 + j];
      #pragma unroll
      for (int i = 0; i < 4; i++)
        #pragma unroll
        for (int j = 0; j < 4; j++)
          acc[i][j] = fmaf(av[i], wvv[j], acc[i][j]);
    }
    __syncthreads();
  }
  #pragma unroll
  for (int i = 0; i < 4; i++) {
    int row = bm + ty * 4 + i;
    if (row < nrows) {
      float4 o;
      o.x = acc[i][0] + bias[bn + tx * 4 + 0];
      o.y = acc[i][1] + bias[bn + tx * 4 + 1];
      o.z = acc[i][2] + bias[bn + tx * 4 + 2];
      o.w = acc[i][3] + bias[bn + tx * 4 + 3];
      *(float4*)(out + (size_t)row * HC + bn + tx * 4) = o;
    }
  }
}

// ---------------- edge phase: per-node online segment softmax + aggregation ----------------
// block = 1 node, wave = 1 head (lane = channel). Self-loop handled inline.

__global__ __launch_bounds__(256)
void gat_edge(const float* __restrict__ xl, const float* __restrict__ xr,
              const float* __restrict__ loopat, const int* __restrict__ rowptr,
              const int* __restrict__ csr_src, const float* __restrict__ csr_ea,
              const float* __restrict__ We, const float* __restrict__ att,
              const float* __restrict__ bias, const float* __restrict__ prelu_w,
              float* __restrict__ out, int n, int is_last) {
  int node = blockIdx.x;
  int lane = threadIdx.x & 63;
  int wv   = threadIdx.x >> 6;
  int hc   = threadIdx.x;          // wv*64 + lane
  float we = We[hc];
  float ah = att[hc];              // att is [H][C] row-major == [hc]
  float xr_v    = xr[(size_t)node * HC + hc];
  float xl_self = xl[(size_t)node * HC + hc];

  // self-loop edge (src = node, eattr = loop_attr[node])
  float m0 = xl_self + xr_v + loopat[node] * we;
  float t0 = (m0 > 0.f ? m0 : NEG * m0) * ah;
  float s = t0;
  #pragma unroll
  for (int off = 32; off >= 1; off >>= 1) s += __shfl_xor(s, off, 64);
  float mx = s, den = 1.f, acc = xl_self;

  int beg = rowptr[node], end = rowptr[node + 1];
  for (int i = beg; i < end; i++) {
    int   sn = csr_src[i];
    float ea = csr_ea[i];
    float v  = xl[(size_t)sn * HC + hc];
    float mm = v + xr_v + ea * we;
    float tt = (mm > 0.f ? mm : NEG * mm) * ah;
    #pragma unroll
    for (int off = 32; off >= 1; off >>= 1) tt += __shfl_xor(tt, off, 64);
    if (tt > mx) {                     // wave-uniform branch
      float r = __expf(mx - tt);
      den = den * r + 1.f;
      acc = acc * r + v;
      mx  = tt;
    } else {
      float p = __expf(tt - mx);
      den += p;
      acc = fmaf(p, v, acc);
    }
  }
  float res = acc / (den + 1e-16f);

  __shared__ float red[4][64];
  red[wv][lane] = res;
  __syncthreads();
  if (wv == 0) {
    float o = 0.25f * (red[0][lane] + red[1][lane] + red[2][lane] + red[3][lane]) + bias[lane];
    if (is_last) o = (o >= 0.f) ? o : prelu_w[lane] * o;
    out[(size_t)node * CCH + lane] = o;
  }
}

// ---------------- launch ----------------

extern "C" void kernel_launch(void* const* d_in, const int* in_sizes, int n_in,
                              void* d_out, int out_size, void* d_ws, size_t ws_size,
                              hipStream_t stream) {
  const float* x     = (const float*)d_in[0];
  const int*   ei    = (const int*)d_in[1];     // int32! (harness passes integer as int)
  const float* eattr = (const float*)d_in[2];
  int N = in_sizes[0] / HC;        // 50000
  int E = in_sizes[1] / 2;         // 800000
  const int* src = ei;
  const int* dst = ei + E;

  const float* Wl[3]  = {(const float*)d_in[3],  (const float*)d_in[10], (const float*)d_in[17]};
  const float* bl[3]  = {(const float*)d_in[4],  (const float*)d_in[11], (const float*)d_in[18]};
  const float* Wr[3]  = {(const float*)d_in[5],  (const float*)d_in[12], (const float*)d_in[19]};
  const float* br[3]  = {(const float*)d_in[6],  (const float*)d_in[13], (const float*)d_in[20]};
  const float* Wev[3] = {(const float*)d_in[7],  (const float*)d_in[14], (const float*)d_in[21]};
  const float* attv[3]= {(const float*)d_in[8],  (const float*)d_in[15], (const float*)d_in[22]};
  const float* bias[3]= {(const float*)d_in[9],  (const float*)d_in[16], (const float*)d_in[23]};
  const float* prelu  = (const float*)d_in[24];

  char* p = (char*)d_ws;
  float* xl     = (float*)p; p += (size_t)N * HC * 4;
  float* xr     = (float*)p; p += (size_t)N * HC * 4;
  float* hbuf   = (float*)p; p += (size_t)N * CCH * 4;
  int*   cnt    = (int*)p;   p += (size_t)N * 4;
  int*   fill   = (int*)p;   p += (size_t)N * 4;
  float* sumf   = (float*)p; p += (size_t)N * 4;
  float* loopat = (float*)p; p += (size_t)N * 4;
  int*   rowptr = (int*)p;   p += (size_t)(N + 8) * 4;
  int*   csr_src= (int*)p;   p += (size_t)E * 4;
  float* csr_ea = (float*)p; p += (size_t)E * 4;

  // zero cnt, fill, sumf (contiguous)
  hipMemsetAsync(cnt, 0, (size_t)N * 3 * 4, stream);

  int tb = 256;
  deg_kernel<<<dim3((E + tb - 1) / tb), dim3(tb), 0, stream>>>(dst, eattr, cnt, sumf, E);
  scan_kernel<<<dim3(1), dim3(1024), 0, stream>>>(cnt, sumf, rowptr, loopat, N);
  csr_fill_kernel<<<dim3((E + tb - 1) / tb), dim3(tb), 0, stream>>>(src, dst, eattr, rowptr,
                                                                    fill, csr_src, csr_ea, E);

  const float* in = x;
  int K = 256;
  for (int l = 0; l < 3; l++) {
    dim3 g((N + 63) / 64, 4);
    gemm_bias<<<g, dim3(256), 0, stream>>>(in, Wl[l], bl[l], xl, N, K);
    gemm_bias<<<g, dim3(256), 0, stream>>>(in, Wr[l], br[l], xr, N, K);
    float* o = (l == 2) ? (float*)d_out : hbuf;
    gat_edge<<<dim3(N), dim3(256), 0, stream>>>(xl, xr, loopat, rowptr, csr_src, csr_ea,
                                                Wev[l], attv[l], bias[l], prelu, o, N, l == 2);
    in = hbuf;
    K = CCH;
  }
}

// Round 5
// 1212.888 us; speedup vs baseline: 1.2821x; 1.2821x over previous
//
#include <hip/hip_runtime.h>

#define HC 256    // H*C
#define CCH 64    // channels
#define NEG 0.2f

// ---------------- preprocessing ----------------

__global__ void deg_kernel(const int* __restrict__ dst,
                           const float* __restrict__ eattr,
                           int* __restrict__ cnt, float* __restrict__ sumf, int E) {
  int e = blockIdx.x * blockDim.x + threadIdx.x;
  if (e >= E) return;
  int d = dst[e];
  atomicAdd(&cnt[d], 1);
  atomicAdd(&sumf[d], eattr[e]);
}

// single-block scan over N counts -> exclusive rowptr; also loop_attr = sum/max(cnt,1)
__global__ void scan_kernel(const int* __restrict__ cnt, const float* __restrict__ sumf,
                            int* __restrict__ rowptr, float* __restrict__ loopat, int n) {
  __shared__ int wsum[16];
  __shared__ int carry_s;
  int tid = threadIdx.x, lane = tid & 63, w = tid >> 6;
  if (tid == 0) carry_s = 0;
  __syncthreads();
  for (int base = 0; base < n; base += 1024) {
    int i = base + tid;
    int v = (i < n) ? cnt[i] : 0;
    int s = v;
    #pragma unroll
    for (int off = 1; off < 64; off <<= 1) {
      int t = __shfl_up(s, off, 64);
      if (lane >= off) s += t;
    }
    if (lane == 63) wsum[w] = s;
    __syncthreads();
    int woff = 0;
    for (int j = 0; j < w; j++) woff += wsum[j];
    int excl = carry_s + woff + s - v;
    if (i < n) {
      rowptr[i] = excl;
      loopat[i] = sumf[i] / fmaxf((float)v, 1.0f);
    }
    __syncthreads();
    if (tid == 1023) carry_s = excl + v;
    __syncthreads();
  }
  if (threadIdx.x == 0) rowptr[n] = carry_s;
}

__global__ void csr_fill_kernel(const int* __restrict__ src,
                                const int* __restrict__ dst,
                                const float* __restrict__ eattr,
                                const int* __restrict__ rowptr,
                                int* __restrict__ fill,
                                int* __restrict__ csr_src, float* __restrict__ csr_ea, int E) {
  int e = blockIdx.x * blockDim.x + threadIdx.x;
  if (e >= E) return;
  int d = dst[e];
  int p = atomicAdd(&fill[d], 1);
  int slot = rowptr[d] + p;
  csr_src[slot] = src[e];
  csr_ea[slot] = eattr[e];
}

// ---------------- fused dual GEMM: xl = A@Wl+bl, xr = A@Wr+br ----------------
// 128x64 C-tile, 256 threads, 8x4 acc/thread. grid = (8, ceil(n/128));
// blockIdx.x<4 -> Wl panel bn=x*64; else Wr panel. 8 consecutive blocks share
// the same A row-panel -> dispatched together -> A fetched ~once from HBM.

__global__ __launch_bounds__(256)
void gemm_dual(const float* __restrict__ A,
               const float* __restrict__ Wl, const float* __restrict__ bl,
               const float* __restrict__ Wr, const float* __restrict__ br,
               float* __restrict__ xl, float* __restrict__ xr,
               int nrows, int K) {
  __shared__ float As[16][132];   // [k][m], padded (132%32=4 banks skew)
  __shared__ float Ws[16][64];    // [k][n]
  const float* W; const float* bb; float* out; int bn;
  if (blockIdx.x < 4) { W = Wl; bb = bl; out = xl; bn = blockIdx.x * 64; }
  else                { W = Wr; bb = br; out = xr; bn = (blockIdx.x - 4) * 64; }
  int bm = blockIdx.y * 128;
  int tx = threadIdx.x & 15;           // N col group (4 cols)
  int ty = threadIdx.x >> 4;           // M row group (8 rows)
  int arow = threadIdx.x & 127;        // A-load row within tile
  int akk  = (threadIdx.x >> 7) * 8;   // 0 or 8 (k sub-slot)
  int wkk  = threadIdx.x >> 4;         // 0..15 k row for W load
  int wc4  = (threadIdx.x & 15) * 4;
  float acc[8][4] = {};
  int row0 = bm + arow;
  for (int k0 = 0; k0 < K; k0 += 16) {
    float4 a0 = make_float4(0.f,0.f,0.f,0.f), a1 = a0;
    if (row0 < nrows) {
      const float* ap = A + (size_t)row0 * K + k0 + akk;
      a0 = *(const float4*)ap;
      a1 = *(const float4*)(ap + 4);
    }
    As[akk+0][arow] = a0.x; As[akk+1][arow] = a0.y;
    As[akk+2][arow] = a0.z; As[akk+3][arow] = a0.w;
    As[akk+4][arow] = a1.x; As[akk+5][arow] = a1.y;
    As[akk+6][arow] = a1.z; As[akk+7][arow] = a1.w;
    *(float4*)&Ws[wkk][wc4] = *(const float4*)(W + (size_t)(k0 + wkk) * HC + bn + wc4);
    __syncthreads();
    #pragma unroll
    for (int k = 0; k < 16; k++) {
      float av[8], wv[4];
      *(float4*)&av[0] = *(const float4*)&As[k][ty * 8];
      *(float4*)&av[4] = *(const float4*)&As[k][ty * 8 + 4];
      *(float4*)&wv[0] = *(const float4*)&Ws[k][tx * 4];
      #pragma unroll
      for (int i = 0; i < 8; i++)
        #pragma unroll
        for (int j = 0; j < 4; j++)
          acc[i][j] = fmaf(av[i], wv[j], acc[i][j]);
    }
    __syncthreads();
  }
  float4 bv = *(const float4*)(bb + bn + tx * 4);
  #pragma unroll
  for (int i = 0; i < 8; i++) {
    int row = bm + ty * 8 + i;
    if (row < nrows) {
      float4 o;
      o.x = acc[i][0] + bv.x;
      o.y = acc[i][1] + bv.y;
      o.z = acc[i][2] + bv.z;
      o.w = acc[i][3] + bv.w;
      *(float4*)(out + (size_t)row * HC + bn + tx * 4) = o;
    }
  }
}

// ---------------- edge phase: batched online segment softmax + aggregation ----------------
// block = 1 node, wave = 1 head (lane = channel). B edges in flight per step.

template<int B>
__device__ __forceinline__ void proc_batch(
    const float* __restrict__ xl, int i,
    const int* __restrict__ csr_src, const float* __restrict__ csr_ea,
    float xr_v, float we, float ah, int hc,
    float& mx, float& den, float& acc) {
  int sn[B]; float ea[B], v[B], s[B];
  #pragma unroll
  for (int j = 0; j < B; j++) { sn[j] = csr_src[i + j]; ea[j] = csr_ea[i + j]; }
  #pragma unroll
  for (int j = 0; j < B; j++) v[j] = xl[(size_t)sn[j] * HC + hc];
  #pragma unroll
  for (int j = 0; j < B; j++) {
    float m = v[j] + xr_v + ea[j] * we;
    s[j] = (m > 0.f ? m : NEG * m) * ah;
  }
  #pragma unroll
  for (int off = 32; off >= 1; off >>= 1)
    #pragma unroll
    for (int j = 0; j < B; j++) s[j] += __shfl_xor(s[j], off, 64);
  float bm = s[0];
  #pragma unroll
  for (int j = 1; j < B; j++) bm = fmaxf(bm, s[j]);
  if (bm > mx) {                      // wave-uniform (post-reduce scores uniform)
    float r = __expf(mx - bm);
    den *= r; acc *= r; mx = bm;
  }
  float ps = 0.f;
  #pragma unroll
  for (int j = 0; j < B; j++) {
    float p = __expf(s[j] - mx);
    ps += p;
    acc = fmaf(p, v[j], acc);
  }
  den += ps;
}

__global__ __launch_bounds__(256)
void gat_edge(const float* __restrict__ xl, const float* __restrict__ xr,
              const float* __restrict__ loopat, const int* __restrict__ rowptr,
              const int* __restrict__ csr_src, const float* __restrict__ csr_ea,
              const float* __restrict__ We, const float* __restrict__ att,
              const float* __restrict__ bias, const float* __restrict__ prelu_w,
              float* __restrict__ out, int n, int is_last) {
  int node = blockIdx.x;
  int lane = threadIdx.x & 63;
  int wv   = threadIdx.x >> 6;
  int hc   = threadIdx.x;          // wv*64 + lane
  float we = We[hc];
  float ah = att[hc];              // att is [H][C] row-major == [hc]
  float xr_v    = xr[(size_t)node * HC + hc];
  float xl_self = xl[(size_t)node * HC + hc];

  // self-loop edge (src = node, eattr = loop_attr[node])
  float m0 = xl_self + xr_v + loopat[node] * we;
  float t0 = (m0 > 0.f ? m0 : NEG * m0) * ah;
  float s = t0;
  #pragma unroll
  for (int off = 32; off >= 1; off >>= 1) s += __shfl_xor(s, off, 64);
  float mx = s, den = 1.f, acc = xl_self;

  int beg = rowptr[node], end = rowptr[node + 1];
  int i = beg;
  for (; i + 8 <= end; i += 8)
    proc_batch<8>(xl, i, csr_src, csr_ea, xr_v, we, ah, hc, mx, den, acc);
  if (i + 4 <= end) {
    proc_batch<4>(xl, i, csr_src, csr_ea, xr_v, we, ah, hc, mx, den, acc);
    i += 4;
  }
  for (; i < end; i++)
    proc_batch<1>(xl, i, csr_src, csr_ea, xr_v, we, ah, hc, mx, den, acc);

  float res = acc / (den + 1e-16f);

  __shared__ float red[4][64];
  red[wv][lane] = res;
  __syncthreads();
  if (wv == 0) {
    float o = 0.25f * (red[0][lane] + red[1][lane] + red[2][lane] + red[3][lane]) + bias[lane];
    if (is_last) o = (o >= 0.f) ? o : prelu_w[lane] * o;
    out[(size_t)node * CCH + lane] = o;
  }
}

// ---------------- launch ----------------

extern "C" void kernel_launch(void* const* d_in, const int* in_sizes, int n_in,
                              void* d_out, int out_size, void* d_ws, size_t ws_size,
                              hipStream_t stream) {
  const float* x     = (const float*)d_in[0];
  const int*   ei    = (const int*)d_in[1];     // int32
  const float* eattr = (const float*)d_in[2];
  int N = in_sizes[0] / HC;        // 50000
  int E = in_sizes[1] / 2;         // 800000
  const int* src = ei;
  const int* dst = ei + E;

  const float* Wl[3]  = {(const float*)d_in[3],  (const float*)d_in[10], (const float*)d_in[17]};
  const float* bl[3]  = {(const float*)d_in[4],  (const float*)d_in[11], (const float*)d_in[18]};
  const float* Wr[3]  = {(const float*)d_in[5],  (const float*)d_in[12], (const float*)d_in[19]};
  const float* br[3]  = {(const float*)d_in[6],  (const float*)d_in[13], (const float*)d_in[20]};
  const float* Wev[3] = {(const float*)d_in[7],  (const float*)d_in[14], (const float*)d_in[21]};
  const float* attv[3]= {(const float*)d_in[8],  (const float*)d_in[15], (const float*)d_in[22]};
  const float* bias[3]= {(const float*)d_in[9],  (const float*)d_in[16], (const float*)d_in[23]};
  const float* prelu  = (const float*)d_in[24];

  char* p = (char*)d_ws;
  float* xl     = (float*)p; p += (size_t)N * HC * 4;
  float* xr     = (float*)p; p += (size_t)N * HC * 4;
  float* hbuf   = (float*)p; p += (size_t)N * CCH * 4;
  int*   cnt    = (int*)p;   p += (size_t)N * 4;
  int*   fill   = (int*)p;   p += (size_t)N * 4;
  float* sumf   = (float*)p; p += (size_t)N * 4;
  float* loopat = (float*)p; p += (size_t)N * 4;
  int*   rowptr = (int*)p;   p += (size_t)(N + 8) * 4;
  int*   csr_src= (int*)p;   p += (size_t)E * 4;
  float* csr_ea = (float*)p; p += (size_t)E * 4;

  // zero cnt, fill, sumf (contiguous)
  hipMemsetAsync(cnt, 0, (size_t)N * 3 * 4, stream);

  int tb = 256;
  deg_kernel<<<dim3((E + tb - 1) / tb), dim3(tb), 0, stream>>>(dst, eattr, cnt, sumf, E);
  scan_kernel<<<dim3(1), dim3(1024), 0, stream>>>(cnt, sumf, rowptr, loopat, N);
  csr_fill_kernel<<<dim3((E + tb - 1) / tb), dim3(tb), 0, stream>>>(src, dst, eattr, rowptr,
                                                                    fill, csr_src, csr_ea, E);

  const float* in = x;
  int K = 256;
  for (int l = 0; l < 3; l++) {
    dim3 g(8, (N + 127) / 128);
    gemm_dual<<<g, dim3(256), 0, stream>>>(in, Wl[l], bl[l], Wr[l], br[l], xl, xr, N, K);
    float* o = (l == 2) ? (float*)d_out : hbuf;
    gat_edge<<<dim3(N), dim3(256), 0, stream>>>(xl, xr, loopat, rowptr, csr_src, csr_ea,
                                                Wev[l], attv[l], bias[l], prelu, o, N, l == 2);
    in = hbuf;
    K = CCH;
  }
}

// Round 6
// 968.288 us; speedup vs baseline: 1.6060x; 1.2526x over previous
//
#include <hip/hip_runtime.h>

#define HC 256    // H*C
#define CCH 64    // channels
#define NEG 0.2f

__device__ __forceinline__ float lk(float m) { return m > 0.f ? m : NEG * m; }

// ---------------- preprocessing ----------------

__global__ void deg_kernel(const int* __restrict__ dst,
                           const float* __restrict__ eattr,
                           int* __restrict__ cnt, float* __restrict__ sumf, int E) {
  int e = blockIdx.x * blockDim.x + threadIdx.x;
  if (e >= E) return;
  int d = dst[e];
  atomicAdd(&cnt[d], 1);
  atomicAdd(&sumf[d], eattr[e]);
}

// single-block scan over N counts -> exclusive rowptr; also loop_attr = sum/max(cnt,1)
__global__ void scan_kernel(const int* __restrict__ cnt, const float* __restrict__ sumf,
                            int* __restrict__ rowptr, float* __restrict__ loopat, int n) {
  __shared__ int wsum[16];
  __shared__ int carry_s;
  int tid = threadIdx.x, lane = tid & 63, w = tid >> 6;
  if (tid == 0) carry_s = 0;
  __syncthreads();
  for (int base = 0; base < n; base += 1024) {
    int i = base + tid;
    int v = (i < n) ? cnt[i] : 0;
    int s = v;
    #pragma unroll
    for (int off = 1; off < 64; off <<= 1) {
      int t = __shfl_up(s, off, 64);
      if (lane >= off) s += t;
    }
    if (lane == 63) wsum[w] = s;
    __syncthreads();
    int woff = 0;
    for (int j = 0; j < w; j++) woff += wsum[j];
    int excl = carry_s + woff + s - v;
    if (i < n) {
      rowptr[i] = excl;
      loopat[i] = sumf[i] / fmaxf((float)v, 1.0f);
    }
    __syncthreads();
    if (tid == 1023) carry_s = excl + v;
    __syncthreads();
  }
  if (threadIdx.x == 0) rowptr[n] = carry_s;
}

__global__ void csr_fill_kernel(const int* __restrict__ src,
                                const int* __restrict__ dst,
                                const float* __restrict__ eattr,
                                const int* __restrict__ rowptr,
                                int* __restrict__ fill,
                                int* __restrict__ csr_src, float* __restrict__ csr_ea, int E) {
  int e = blockIdx.x * blockDim.x + threadIdx.x;
  if (e >= E) return;
  int d = dst[e];
  int p = atomicAdd(&fill[d], 1);
  int slot = rowptr[d] + p;
  csr_src[slot] = src[e];
  csr_ea[slot] = eattr[e];
}

// ---------------- fused dual GEMM: xl = A@Wl+bl, xr = A@Wr+br ----------------

__global__ __launch_bounds__(256)
void gemm_dual(const float* __restrict__ A,
               const float* __restrict__ Wl, const float* __restrict__ bl,
               const float* __restrict__ Wr, const float* __restrict__ br,
               float* __restrict__ xl, float* __restrict__ xr,
               int nrows, int K) {
  __shared__ float As[16][132];   // [k][m], padded
  __shared__ float Ws[16][64];    // [k][n]
  const float* W; const float* bb; float* out; int bn;
  if (blockIdx.x < 4) { W = Wl; bb = bl; out = xl; bn = blockIdx.x * 64; }
  else                { W = Wr; bb = br; out = xr; bn = (blockIdx.x - 4) * 64; }
  int bm = blockIdx.y * 128;
  int tx = threadIdx.x & 15;           // N col group (4 cols)
  int ty = threadIdx.x >> 4;           // M row group (8 rows)
  int arow = threadIdx.x & 127;        // A-load row within tile
  int akk  = (threadIdx.x >> 7) * 8;   // 0 or 8
  int wkk  = threadIdx.x >> 4;         // 0..15 k row for W load
  int wc4  = (threadIdx.x & 15) * 4;
  float acc[8][4] = {};
  int row0 = bm + arow;
  for (int k0 = 0; k0 < K; k0 += 16) {
    float4 a0 = make_float4(0.f,0.f,0.f,0.f), a1 = a0;
    if (row0 < nrows) {
      const float* ap = A + (size_t)row0 * K + k0 + akk;
      a0 = *(const float4*)ap;
      a1 = *(const float4*)(ap + 4);
    }
    As[akk+0][arow] = a0.x; As[akk+1][arow] = a0.y;
    As[akk+2][arow] = a0.z; As[akk+3][arow] = a0.w;
    As[akk+4][arow] = a1.x; As[akk+5][arow] = a1.y;
    As[akk+6][arow] = a1.z; As[akk+7][arow] = a1.w;
    *(float4*)&Ws[wkk][wc4] = *(const float4*)(W + (size_t)(k0 + wkk) * HC + bn + wc4);
    __syncthreads();
    #pragma unroll
    for (int k = 0; k < 16; k++) {
      float av[8], wv[4];
      *(float4*)&av[0] = *(const float4*)&As[k][ty * 8];
      *(float4*)&av[4] = *(const float4*)&As[k][ty * 8 + 4];
      *(float4*)&wv[0] = *(const float4*)&Ws[k][tx * 4];
      #pragma unroll
      for (int i = 0; i < 8; i++)
        #pragma unroll
        for (int j = 0; j < 4; j++)
          acc[i][j] = fmaf(av[i], wv[j], acc[i][j]);
    }
    __syncthreads();
  }
  float4 bv = *(const float4*)(bb + bn + tx * 4);
  #pragma unroll
  for (int i = 0; i < 8; i++) {
    int row = bm + ty * 8 + i;
    if (row < nrows) {
      float4 o;
      o.x = acc[i][0] + bv.x;
      o.y = acc[i][1] + bv.y;
      o.z = acc[i][2] + bv.z;
      o.w = acc[i][3] + bv.w;
      *(float4*)(out + (size_t)row * HC + bn + tx * 4) = o;
    }
  }
}

// ---------------- edge phase ----------------
// block = node (4 waves). Each WAVE processes a contiguous quarter of the
// node's edge list, handling the WHOLE edge (all 4 heads): lane l holds
// channels 4l..4l+3 (float4), head h = l>>4. Score reduce = 4 shfl_xor steps
// within the 16-lane head group. Branchless per-head online softmax;
// 4-wave merge via LDS at the end.

template<int B>
__device__ __forceinline__ void proc_edges(
    const float* __restrict__ xl, int i,
    const int* __restrict__ csr_src, const float* __restrict__ csr_ea,
    const float4 xr4, const float4 we4, const float4 ah4, int l4,
    float& mx, float& den, float4& acc) {
  int sn[B]; float ea[B]; float4 v[B]; float s[B];
  #pragma unroll
  for (int j = 0; j < B; j++) { sn[j] = csr_src[i + j]; ea[j] = csr_ea[i + j]; }
  #pragma unroll
  for (int j = 0; j < B; j++)
    v[j] = *(const float4*)(xl + (size_t)sn[j] * HC + l4);
  #pragma unroll
  for (int j = 0; j < B; j++) {
    float mx_ = fmaf(ea[j], we4.x, v[j].x + xr4.x);
    float my_ = fmaf(ea[j], we4.y, v[j].y + xr4.y);
    float mz_ = fmaf(ea[j], we4.z, v[j].z + xr4.z);
    float mw_ = fmaf(ea[j], we4.w, v[j].w + xr4.w);
    s[j] = lk(mx_) * ah4.x + lk(my_) * ah4.y + lk(mz_) * ah4.z + lk(mw_) * ah4.w;
  }
  #pragma unroll
  for (int off = 8; off >= 1; off >>= 1)
    #pragma unroll
    for (int j = 0; j < B; j++) s[j] += __shfl_xor(s[j], off, 64);
  float bm = s[0];
  #pragma unroll
  for (int j = 1; j < B; j++) bm = fmaxf(bm, s[j]);
  float newm = fmaxf(mx, bm);
  float r = __expf(mx - newm);
  den *= r; acc.x *= r; acc.y *= r; acc.z *= r; acc.w *= r;
  #pragma unroll
  for (int j = 0; j < B; j++) {
    float p = __expf(s[j] - newm);
    den += p;
    acc.x = fmaf(p, v[j].x, acc.x);
    acc.y = fmaf(p, v[j].y, acc.y);
    acc.z = fmaf(p, v[j].z, acc.z);
    acc.w = fmaf(p, v[j].w, acc.w);
  }
  mx = newm;
}

__global__ __launch_bounds__(256)
void gat_edge(const float* __restrict__ xl, const float* __restrict__ xr,
              const float* __restrict__ loopat, const int* __restrict__ rowptr,
              const int* __restrict__ csr_src, const float* __restrict__ csr_ea,
              const float* __restrict__ We, const float* __restrict__ att,
              const float* __restrict__ bias, const float* __restrict__ prelu_w,
              float* __restrict__ out, int n, int is_last) {
  int node = blockIdx.x;
  int l    = threadIdx.x & 63;
  int wv   = threadIdx.x >> 6;
  int l4   = l * 4;
  float4 we4 = *(const float4*)(We + l4);
  float4 ah4 = *(const float4*)(att + l4);
  float4 xr4 = *(const float4*)(xr + (size_t)node * HC + l4);

  float mx, den; float4 acc;
  if (wv == 0) {
    // self-loop edge
    float4 vs = *(const float4*)(xl + (size_t)node * HC + l4);
    float la = loopat[node];
    float mx_ = fmaf(la, we4.x, vs.x + xr4.x);
    float my_ = fmaf(la, we4.y, vs.y + xr4.y);
    float mz_ = fmaf(la, we4.z, vs.z + xr4.z);
    float mw_ = fmaf(la, we4.w, vs.w + xr4.w);
    float t = lk(mx_) * ah4.x + lk(my_) * ah4.y + lk(mz_) * ah4.z + lk(mw_) * ah4.w;
    #pragma unroll
    for (int off = 8; off >= 1; off >>= 1) t += __shfl_xor(t, off, 64);
    mx = t; den = 1.f; acc = vs;                 // p = exp(t-t) = 1
  } else {
    mx = -3.4e38f; den = 0.f; acc = make_float4(0.f, 0.f, 0.f, 0.f);
  }

  int beg = rowptr[node], end = rowptr[node + 1];
  int per = (end - beg + 3) >> 2;
  int wbeg = beg + wv * per;
  int wend = min(wbeg + per, end);
  int i = wbeg;
  for (; i + 4 <= wend; i += 4)
    proc_edges<4>(xl, i, csr_src, csr_ea, xr4, we4, ah4, l4, mx, den, acc);
  for (; i < wend; i++)
    proc_edges<1>(xl, i, csr_src, csr_ea, xr4, we4, ah4, l4, mx, den, acc);

  // ---- merge 4 waves' per-head partial states ----
  __shared__ float  s_mx[4][4];     // [wave][head]
  __shared__ float  s_den[4][4];
  __shared__ float4 s_acc[4][64];   // [wave][lane]
  int h = l >> 4;
  s_acc[wv][l] = acc;
  if ((l & 15) == 0) { s_mx[wv][h] = mx; s_den[wv][h] = den; }
  __syncthreads();
  if (wv == 0) {
    float M = fmaxf(fmaxf(s_mx[0][h], s_mx[1][h]), fmaxf(s_mx[2][h], s_mx[3][h]));
    float dt = 0.f;
    float4 a = make_float4(0.f, 0.f, 0.f, 0.f);
    #pragma unroll
    for (int w = 0; w < 4; w++) {
      float f = __expf(s_mx[w][h] - M);
      dt = fmaf(s_den[w][h], f, dt);
      float4 aw = s_acc[w][l];
      a.x = fmaf(aw.x, f, a.x);
      a.y = fmaf(aw.y, f, a.y);
      a.z = fmaf(aw.z, f, a.z);
      a.w = fmaf(aw.w, f, a.w);
    }
    float inv = 1.f / (dt + 1e-16f);
    a.x *= inv; a.y *= inv; a.z *= inv; a.w *= inv;
    // sum over the 4 heads: lanes l, l^16, l^32, l^48 hold the same
    // within-head channel for different heads
    a.x += __shfl_xor(a.x, 16, 64); a.x += __shfl_xor(a.x, 32, 64);
    a.y += __shfl_xor(a.y, 16, 64); a.y += __shfl_xor(a.y, 32, 64);
    a.z += __shfl_xor(a.z, 16, 64); a.z += __shfl_xor(a.z, 32, 64);
    a.w += __shfl_xor(a.w, 16, 64); a.w += __shfl_xor(a.w, 32, 64);
    if (l < 16) {
      int c = l * 4;
      float4 bv = *(const float4*)(bias + c);
      float4 o;
      o.x = 0.25f * a.x + bv.x;
      o.y = 0.25f * a.y + bv.y;
      o.z = 0.25f * a.z + bv.z;
      o.w = 0.25f * a.w + bv.w;
      if (is_last) {
        float4 pw = *(const float4*)(prelu_w + c);
        o.x = o.x >= 0.f ? o.x : pw.x * o.x;
        o.y = o.y >= 0.f ? o.y : pw.y * o.y;
        o.z = o.z >= 0.f ? o.z : pw.z * o.z;
        o.w = o.w >= 0.f ? o.w : pw.w * o.w;
      }
      *(float4*)(out + (size_t)node * CCH + c) = o;
    }
  }
}

// ---------------- launch ----------------

extern "C" void kernel_launch(void* const* d_in, const int* in_sizes, int n_in,
                              void* d_out, int out_size, void* d_ws, size_t ws_size,
                              hipStream_t stream) {
  const float* x     = (const float*)d_in[0];
  const int*   ei    = (const int*)d_in[1];     // int32
  const float* eattr = (const float*)d_in[2];
  int N = in_sizes[0] / HC;        // 50000
  int E = in_sizes[1] / 2;         // 800000
  const int* src = ei;
  const int* dst = ei + E;

  const float* Wl[3]  = {(const float*)d_in[3],  (const float*)d_in[10], (const float*)d_in[17]};
  const float* bl[3]  = {(const float*)d_in[4],  (const float*)d_in[11], (const float*)d_in[18]};
  const float* Wr[3]  = {(const float*)d_in[5],  (const float*)d_in[12], (const float*)d_in[19]};
  const float* br[3]  = {(const float*)d_in[6],  (const float*)d_in[13], (const float*)d_in[20]};
  const float* Wev[3] = {(const float*)d_in[7],  (const float*)d_in[14], (const float*)d_in[21]};
  const float* attv[3]= {(const float*)d_in[8],  (const float*)d_in[15], (const float*)d_in[22]};
  const float* bias[3]= {(const float*)d_in[9],  (const float*)d_in[16], (const float*)d_in[23]};
  const float* prelu  = (const float*)d_in[24];

  char* p = (char*)d_ws;
  float* xl     = (float*)p; p += (size_t)N * HC * 4;
  float* xr     = (float*)p; p += (size_t)N * HC * 4;
  float* hbuf   = (float*)p; p += (size_t)N * CCH * 4;
  int*   cnt    = (int*)p;   p += (size_t)N * 4;
  int*   fill   = (int*)p;   p += (size_t)N * 4;
  float* sumf   = (float*)p; p += (size_t)N * 4;
  float* loopat = (float*)p; p += (size_t)N * 4;
  int*   rowptr = (int*)p;   p += (size_t)(N + 8) * 4;
  int*   csr_src= (int*)p;   p += (size_t)E * 4;
  float* csr_ea = (float*)p; p += (size_t)E * 4;

  hipMemsetAsync(cnt, 0, (size_t)N * 3 * 4, stream);

  int tb = 256;
  deg_kernel<<<dim3((E + tb - 1) / tb), dim3(tb), 0, stream>>>(dst, eattr, cnt, sumf, E);
  scan_kernel<<<dim3(1), dim3(1024), 0, stream>>>(cnt, sumf, rowptr, loopat, N);
  csr_fill_kernel<<<dim3((E + tb - 1) / tb), dim3(tb), 0, stream>>>(src, dst, eattr, rowptr,
                                                                    fill, csr_src, csr_ea, E);

  const float* in = x;
  int K = 256;
  for (int l = 0; l < 3; l++) {
    dim3 g(8, (N + 127) / 128);
    gemm_dual<<<g, dim3(256), 0, stream>>>(in, Wl[l], bl[l], Wr[l], br[l], xl, xr, N, K);
    float* o = (l == 2) ? (float*)d_out : hbuf;
    gat_edge<<<dim3(N), dim3(256), 0, stream>>>(xl, xr, loopat, rowptr, csr_src, csr_ea,
                                                Wev[l], attv[l], bias[l], prelu, o, N, l == 2);
    in = hbuf;
    K = CCH;
  }
}